// Round 1
// baseline (217.804 us; speedup 1.0000x reference)
//
#include <hip/hip_runtime.h>

#ifndef __has_builtin
#define __has_builtin(x) 0
#endif

// Problem constants (from reference): B=8, N=1048576, Z=1024, IN_DIM=1, HID=16
#define BB  8
#define NN  1048576
#define ZZ  1024
#define HID 16

__device__ __forceinline__ float fexp2(float v) {
#if __has_builtin(__builtin_amdgcn_exp2f)
    return __builtin_amdgcn_exp2f(v);   // raw v_exp_f32
#else
    return exp2f(v);
#endif
}
__device__ __forceinline__ float frcp(float v) {
#if __has_builtin(__builtin_amdgcn_rcpf)
    return __builtin_amdgcn_rcpf(v);    // raw v_rcp_f32
#else
    return 1.0f / v;
#endif
}

// Main fused kernel: each block processes a contiguous chunk of one batch row,
// accumulates per-bucket (sum, count) in LDS, then flushes partials to ws.
// PARTIALS=true : flush = plain stores to per-block slice of ws (preferred)
// PARTIALS=false: flush = global atomicAdd into per-batch slice (small-ws fallback)
template <bool PARTIALS>
__global__ __launch_bounds__(256, 4)
void fik_main(const float* __restrict__ x, const float* __restrict__ y,
              const float* __restrict__ z,
              const float* __restrict__ W1, const float* __restrict__ b1,
              const float* __restrict__ gamma, const float* __restrict__ beta,
              const float* __restrict__ W2, const float* __restrict__ b2,
              float* __restrict__ ws, int chunks)
{
    __shared__ float s_sum[ZZ];
    __shared__ float s_cnt[ZZ];
    for (int i = threadIdx.x; i < ZZ; i += 256) { s_sum[i] = 0.f; s_cnt[i] = 0.f; }

    const int b = blockIdx.x / chunks;
    const int c = blockIdx.x - b * chunks;
    const int elems = NN / chunks;

    // Uniform weight loads -> scalar (s_load) registers
    float w1x[HID], w1z[HID], w1y[HID], vb1[HID], vg[HID], vbt[HID], vw2[HID];
#pragma unroll
    for (int j = 0; j < HID; ++j) {
        w1x[j] = W1[j];
        w1z[j] = W1[HID + j];
        w1y[j] = W1[2 * HID + j];
        vb1[j] = b1[j];
        vg[j]  = gamma[j];
        vbt[j] = beta[j];
        vw2[j] = W2[j];
    }
    const float vb2  = b2[0];
    const float z0   = z[0];
    const float dz   = z[1] - z0;
    const float zoff = z0 + 0.5f * dz;   // z0 + dz/2 (z0==0 so exact)

    __syncthreads();

    const size_t base = (size_t)b * NN + (size_t)c * elems;
    const float4* __restrict__ x4 = (const float4*)(x + base);
    const float4* __restrict__ y4 = (const float4*)(y + base);
    const int iters = elems >> 10;   // elems / (256 threads * 4 per float4)

    for (int it = 0; it < iters; ++it) {
        const int vi = it * 256 + (int)threadIdx.x;
        const float4 xv = x4[vi];
        const float4 yv = y4[vi];
        const float xs[4] = {xv.x, xv.y, xv.z, xv.w};
        const float ys[4] = {yv.x, yv.y, yv.z, yv.w};
#pragma unroll
        for (int e = 0; e < 4; ++e) {
            const float xe = xs[e];
            const float ye = ys[e];
            // bucket index: ceil((x - z0 - dz/2)/dz)  (IEEE f32 div to match numpy)
            const float qf = (xe - zoff) / dz;
            int idx = (int)ceilf(qf);
            idx = idx < 0 ? 0 : (idx > ZZ - 1 ? ZZ - 1 : idx);
            const float zg = z[idx];   // 4 KB table, L1-resident gather

            // h = [x, zg, y] @ W1 + b1  (pass 1: values + LN stats)
            float h[HID];
            float s = 0.f, ss = 0.f;
#pragma unroll
            for (int j = 0; j < HID; ++j) {
                const float t = fmaf(xe, w1x[j], fmaf(zg, w1z[j], fmaf(ye, w1y[j], vb1[j])));
                h[j] = t;
                s += t;
                ss = fmaf(t, t, ss);
            }
            const float mu   = s * (1.f / HID);
            const float var  = fmaf(ss, 1.f / HID, -mu * mu);   // biased var (jnp default)
            const float rsig = rsqrtf(var + 1e-5f);

            // pass 2: LayerNorm affine -> gelu -> dot W2
            float acc = 0.f;
#pragma unroll
            for (int j = 0; j < HID; ++j) {
                const float gj = rsig * vg[j];
                const float a  = fmaf(h[j], gj, fmaf(-mu, gj, vbt[j]));
                // gelu(a) ~ a * sigmoid(1.5957691a + 0.07135481a^3)
                //        = a / (1 + exp2(a*(K1 + K2*a^2))),  K1=-2*sqrt(2/pi)*log2e
                const float a2 = a * a;
                const float qd = a * fmaf(-0.10294335f, a2, -2.3022082f);
                const float g  = a * frcp(1.f + fexp2(qd));
                acc = fmaf(g, vw2[j], acc);
            }
            const float out = (acc + vb2) * ye;

            atomicAdd(&s_sum[idx], out);   // ds_add_f32, fire-and-forget
            atomicAdd(&s_cnt[idx], 1.0f);
        }
    }

    __syncthreads();
    if (PARTIALS) {
        float* dst = ws + (size_t)blockIdx.x * (2 * ZZ);
        for (int i = threadIdx.x; i < ZZ; i += 256) {
            dst[i]      = s_sum[i];
            dst[ZZ + i] = s_cnt[i];
        }
    } else {
        float* dst = ws + (size_t)b * (2 * ZZ);
        for (int i = threadIdx.x; i < ZZ; i += 256) {
            atomicAdd(&dst[i],      s_sum[i]);
            atomicAdd(&dst[ZZ + i], s_cnt[i]);
        }
    }
}

// Reduce per-block partials -> mean, write (B, 1, Z) output
__global__ void fik_reduce(const float* __restrict__ ws, float* __restrict__ out, int chunks)
{
    const int t = blockIdx.x * 256 + (int)threadIdx.x;
    if (t >= BB * ZZ) return;
    const int b  = t >> 10;        // / ZZ
    const int zi = t & (ZZ - 1);
    float s = 0.f, cnt = 0.f;
    for (int c = 0; c < chunks; ++c) {
        const float* p = ws + (size_t)(b * chunks + c) * (2 * ZZ);
        s   += p[zi];
        cnt += p[ZZ + zi];
    }
    out[t] = s / fmaxf(cnt, 1.0f);
}

extern "C" void kernel_launch(void* const* d_in, const int* in_sizes, int n_in,
                              void* d_out, int out_size, void* d_ws, size_t ws_size,
                              hipStream_t stream)
{
    const float* x     = (const float*)d_in[0];
    const float* y     = (const float*)d_in[1];
    const float* z     = (const float*)d_in[2];
    const float* W1    = (const float*)d_in[3];
    const float* b1    = (const float*)d_in[4];
    const float* gamma = (const float*)d_in[5];
    const float* beta  = (const float*)d_in[6];
    const float* W2    = (const float*)d_in[7];
    const float* b2    = (const float*)d_in[8];
    float* out = (float*)d_out;
    float* ws  = (float*)d_ws;

    const int chunks = 128;                      // blocks per batch row -> 1024 blocks total
    const size_t need = (size_t)BB * chunks * 2 * ZZ * sizeof(float);   // 8 MB
    const bool partials = (ws_size >= need);

    dim3 block(256);
    dim3 grid(BB * chunks);
    if (partials) {
        fik_main<true><<<grid, block, 0, stream>>>(x, y, z, W1, b1, gamma, beta, W2, b2, ws, chunks);
        fik_reduce<<<(BB * ZZ + 255) / 256, 256, 0, stream>>>(ws, out, chunks);
    } else {
        hipMemsetAsync(d_ws, 0, (size_t)BB * 2 * ZZ * sizeof(float), stream);
        fik_main<false><<<grid, block, 0, stream>>>(x, y, z, W1, b1, gamma, beta, W2, b2, ws, chunks);
        fik_reduce<<<(BB * ZZ + 255) / 256, 256, 0, stream>>>(ws, out, 1);
    }
}